// Round 4
// baseline (741.809 us; speedup 1.0000x reference)
//
#include <hip/hip_runtime.h>

// ExtractSearchWindows: out[b,h,w,rr,tt] = (uint8)Q[b, h+off+ry+ty, w+off+rx+tx],
// Q = input padded by 6; stored as INT32 (harness reads uint8 ref via int32 path).
// Write-BW bound: 708 MB stores. R3 post-mortem: kernel ~263us vs 113us roofline;
// hot loop was LDS-table + straddle-branch heavy.
// R4 structure: 4 pixels * 2401 dwords = exactly 2401 aligned quads ("supergroup").
// Each thread owns 10 fixed quads per group; quad -> (p_in_group, patch offset)
// is group-invariant -> hoisted to 40 VGPRs at setup. Hot loop: 4 ds_read_b32 +
// 1 aligned nontemporal dwordx4 store per quad, zero divisions, zero straddle.

#define KT 7
#define K2 49
#define MAX_SR 3
#define B_ 2
#define H_ 192
#define W_ 192
#define PAD 6
#define PX 48               // pixels (w) per block; grid = 4*192*2 = 1536 = 6/CU
#define PCOLS (PX + 2*PAD)  // 60
#define PSTRIDE 61
#define PROWS 13
#define NTHREADS 256
#define RMAX 10             // ceil(2401/256) rounds of quads per 4-pixel group

typedef int vint4 __attribute__((ext_vector_type(4)));

__global__ __launch_bounds__(NTHREADS) void esw_kernel(
    const float* __restrict__ in, int* __restrict__ out,
    int cv, int offset, int d /* = cv*cv*49, odd, <= 2401 */)
{
    __shared__ int patch[PROWS * PSTRIDE];

    const int tid = threadIdx.x;
    const int w0 = blockIdx.x * PX;
    const int h  = blockIdx.y;
    const int b  = blockIdx.z;

    // Stage patch: rows h-6..h+6, cols w0-6..w0+53, uint8 trunc applied.
    const float* inb = in + b * (H_ * W_);
    for (int i = tid; i < PROWS * PCOLS; i += NTHREADS) {
        int dy = i / PCOLS;            // const divisor
        int dx = i - dy * PCOLS;
        int y = h + dy - PAD;
        int x = w0 + dx - PAD;
        int v = 0;
        if ((unsigned)y < (unsigned)H_ && (unsigned)x < (unsigned)W_)
            v = (int)inb[y * W_ + x];  // trunc; vals in [0,255)
        patch[dy * PSTRIDE + dx] = v;
    }

    // Group-invariant per-thread tables: quad q = tid + 256r covers global
    // dwords 4q..4q+3 of a 4-pixel group; element u -> pixel p_in = jj/d,
    // j = jj mod d, patch offset e = dy*PSTRIDE + (off+rx+tx) + p_in.
    int e[RMAX][4];
    #pragma unroll
    for (int r = 0; r < RMAX; ++r) {
        int q = tid + NTHREADS * r;
        int j4 = 4 * q;
        #pragma unroll
        for (int u = 0; u < 4; ++u) {
            int jj = j4 + u;
            if (jj >= 4 * d) jj = 4 * d - 1;  // clamp for inactive rounds
            int p_in = jj / d;                 // runtime div, setup only
            int j  = jj - p_in * d;
            int rr = j / K2;                   // const divisor 49
            int tt = j - rr * K2;
            int ry = rr / cv;                  // runtime div, setup only
            int rx = rr - ry * cv;
            int ty = tt / KT;                  // const divisor 7
            int tx = tt - ty * KT;
            e[r][u] = (offset + ry + ty) * PSTRIDE + (offset + rx + tx) + p_in;
        }
    }
    __syncthreads();

    long long p0 = (long long)(b * H_ + h) * W_ + w0;
    int* op = out + p0 * (long long)d;   // block base; 16B-aligned (48*d dwords)

    // 12 groups of 4 pixels; per group: d quads, thread t owns q = t + 256r.
    for (int gidx = 0; gidx < PX / 4; ++gidx) {
        const int pb = 4 * gidx;         // pixel base of this group
        #pragma unroll
        for (int r = 0; r < RMAX; ++r) {
            int q = tid + NTHREADS * r;
            if (q < d) {                 // full for r<9 at d=2401; masked last round
                vint4 v;
                v.x = patch[e[r][0] + pb];
                v.y = patch[e[r][1] + pb];
                v.z = patch[e[r][2] + pb];
                v.w = patch[e[r][3] + pb];
                __builtin_nontemporal_store(v, (vint4*)(op + 4 * q));
            }
        }
        op += 4 * d;                     // advance 4 pixels
    }
}

extern "C" void kernel_launch(void* const* d_in, const int* in_sizes, int n_in,
                              void* d_out, int out_size, void* d_ws, size_t ws_size,
                              hipStream_t stream) {
    const float* in = (const float*)d_in[0];
    int* out = (int*)d_out;

    // out_size = B*H*W * cv^2 * 49
    int cv2 = out_size / (B_ * H_ * W_ * K2);
    int cv = 1;
    while (cv * cv < cv2) ++cv;
    int offset = MAX_SR - (cv - 1) / 2;
    int d = cv2 * K2;

    dim3 grid(W_ / PX, H_, B_);
    esw_kernel<<<grid, NTHREADS, 0, stream>>>(in, out, cv, offset, d);
}

// Round 5
// 724.756 us; speedup vs baseline: 1.0235x; 1.0235x over previous
//
#include <hip/hip_runtime.h>

// ExtractSearchWindows: out[b,h,w,rr,tt] = (uint8)Q[b, h+off+ry+ty, w+off+rx+tx],
// Q = input padded by 6; stored as INT32 (harness reads uint8 ref via int32 path).
// R4 post-mortem: issue-bound (~9 instr per 16B store) + 8-way LDS bank conflicts
// (lane-stride-4 gathers). R5: loop-swap so the 12 per-group values of one table
// entry are patch[e+4g] -> ds_read2_b32 with constant offsets (2 dwords/instr);
// phi-swizzle phi(c)=c+c/4 turns lane stride 4 into bank stride 5 (conflict-free)
// while keeping read2 offsets constant (phi(e+4g)=phi(e)+5g). Plain (not NT)
// dwordx4 stores — harness fill proves plain stores sustain 6.24 TB/s.

#define KT 7
#define K2 49
#define MAX_SR 3
#define B_ 2
#define H_ 192
#define W_ 192
#define PAD 6
#define PX 48               // pixels (w) per block; grid = 4*192*2 = 1536 = 6/CU
#define PCOLS (PX + 2*PAD)  // 60
#define PSTRIDE 61
#define PROWS 13
#define NTHREADS 256
#define RMAX 10             // ceil(2401/256) quads per thread per 4-pixel group
#define NG (PX / 4)         // 12 four-pixel groups per block

typedef int vint4 __attribute__((ext_vector_type(4)));

__global__ __launch_bounds__(NTHREADS) void esw_kernel(
    const float* __restrict__ in, int* __restrict__ out,
    int cv, int offset, int d /* = cv*cv*49 */, int cvmagic /* ceil(65536/cv) */)
{
    __shared__ int sw[1024];   // phi-swizzled patch: sw[c + (c>>2)] = patch[c]

    const int tid = threadIdx.x;
    const int w0 = blockIdx.x * PX;
    const int h  = blockIdx.y;
    const int b  = blockIdx.z;

    // Stage patch (rows h-6..h+6, cols w0-6..w0+53), uint8 trunc, phi-swizzled.
    const float* inb = in + b * (H_ * W_);
    for (int i = tid; i < PROWS * PCOLS; i += NTHREADS) {
        int dy = i / PCOLS;            // const divisor
        int dx = i - dy * PCOLS;
        int y = h + dy - PAD;
        int x = w0 + dx - PAD;
        int v = 0;
        if ((unsigned)y < (unsigned)H_ && (unsigned)x < (unsigned)W_)
            v = (int)inb[y * W_ + x];  // trunc; vals in [0,255)
        int c = dy * PSTRIDE + dx;
        sw[c + (c >> 2)] = v;
    }

    // Per-thread group-invariant tables: quad q = tid + 256r covers dwords
    // 4q..4q+3 of each 4-pixel group. fe[r][u] = phi(patch offset for elem u).
    int fe[RMAX][4];
    #pragma unroll
    for (int r = 0; r < RMAX; ++r) {
        int j4 = 4 * (tid + NTHREADS * r);
        #pragma unroll
        for (int u = 0; u < 4; ++u) {
            int jj = j4 + u;
            if (jj >= 4 * d) jj = 4 * d - 1;            // clamp inactive rounds
            int p_in = (jj >= d) + (jj >= 2 * d) + (jj >= 3 * d);
            int j  = jj - p_in * d;
            int rr = j / K2;                            // const divisor 49
            int tt = j - rr * K2;
            int ry = (rr * cvmagic) >> 16;              // rr / cv (rr < 49)
            int rx = rr - ry * cv;
            int ty = tt / KT;                           // const divisor 7
            int tx = tt - ty * KT;
            int e = (offset + ry + ty) * PSTRIDE + (offset + rx + tx) + p_in;
            fe[r][u] = e + (e >> 2);                    // phi(e)
        }
    }
    __syncthreads();

    long long p0 = (long long)(b * H_ + h) * W_ + w0;
    int* op = out + p0 * (long long)d;   // 16B-aligned block base (48*d dwords)

    // Hot loop: r outer (quad id), group-pairs inner. Reads sw[fe + 5g] /
    // sw[fe + 5g + 5] share one base VGPR + const offsets -> ds_read2_b32.
    #pragma unroll
    for (int r = 0; r < RMAX; ++r) {
        int q = tid + NTHREADS * r;
        if (q < d) {
            int* oq = op + 4 * q;
            #pragma unroll
            for (int g = 0; g < NG; g += 2) {
                vint4 a, c2;
                a.x  = sw[fe[r][0] + 5 * g];
                c2.x = sw[fe[r][0] + 5 * g + 5];
                a.y  = sw[fe[r][1] + 5 * g];
                c2.y = sw[fe[r][1] + 5 * g + 5];
                a.z  = sw[fe[r][2] + 5 * g];
                c2.z = sw[fe[r][2] + 5 * g + 5];
                a.w  = sw[fe[r][3] + 5 * g];
                c2.w = sw[fe[r][3] + 5 * g + 5];
                *(vint4*)(oq + (long long)g * 4 * d)       = a;
                *(vint4*)(oq + (long long)(g + 1) * 4 * d) = c2;
            }
        }
    }
}

extern "C" void kernel_launch(void* const* d_in, const int* in_sizes, int n_in,
                              void* d_out, int out_size, void* d_ws, size_t ws_size,
                              hipStream_t stream) {
    const float* in = (const float*)d_in[0];
    int* out = (int*)d_out;

    // out_size = B*H*W * cv^2 * 49
    int cv2 = out_size / (B_ * H_ * W_ * K2);
    int cv = 1;
    while (cv * cv < cv2) ++cv;
    int offset = MAX_SR - (cv - 1) / 2;
    int d = cv2 * K2;
    int cvmagic = 65536 / cv + 1;

    dim3 grid(W_ / PX, H_, B_);
    esw_kernel<<<grid, NTHREADS, 0, stream>>>(in, out, cv, offset, d, cvmagic);
}

// Round 6
// 724.356 us; speedup vs baseline: 1.0241x; 1.0006x over previous
//
#include <hip/hip_runtime.h>

// ExtractSearchWindows: out[b,h,w,rr,tt] = (uint8)Q[b, h+off+ry+ty, w+off+rx+tx],
// Q = input padded by 6; stored as INT32 (harness reads uint8 ref via int32 path).
// R3/R4/R5 post-mortem: three different hot loops all ~270us (2.6 TB/s) -> CU-side
// (LDS/issue) has >=8x margin; limiter is store-path concurrency. All rounds had
// only 24 waves/CU. R6: 512-thr blocks, PX=32, __launch_bounds__(512,8) -> 64-VGPR
// cap -> 32 waves/CU; reg quad-table shrinks to fe[5][4]=20 VGPRs; 128B-aligned
// block bases; unrolled g-loop for more independent in-flight stores.

#define KT 7
#define K2 49
#define MAX_SR 3
#define B_ 2
#define H_ 192
#define W_ 192
#define PAD 6
#define PX 32               // pixels (w) per block; grid = 6*192*2 = 2304 blocks
#define PCOLS (PX + 2*PAD)  // 44
#define PSTRIDE 45
#define PROWS 13
#define NTHREADS 512
#define RMAX 5              // ceil(2401/512) quads per thread per 4-pixel group
#define NG (PX / 4)         // 8 four-pixel groups per block

typedef int vint4 __attribute__((ext_vector_type(4)));

__global__ __launch_bounds__(NTHREADS, 8) void esw_kernel(
    const float* __restrict__ in, int* __restrict__ out,
    int cv, int offset, int d /* = cv*cv*49 */, int cvmagic /* 65536/cv + 1 */)
{
    __shared__ int sw[((PROWS * PSTRIDE) * 5) / 4 + 4];  // phi-swizzled patch

    const int tid = threadIdx.x;
    const int w0 = blockIdx.x * PX;
    const int h  = blockIdx.y;
    const int b  = blockIdx.z;

    // Stage patch (rows h-6..h+6, cols w0-6..w0+37), uint8 trunc, phi-swizzled:
    // sw[c + (c>>2)] = patch[c], phi strictly increasing -> injective.
    const float* inb = in + b * (H_ * W_);
    for (int i = tid; i < PROWS * PCOLS; i += NTHREADS) {
        int dy = i / PCOLS;            // const divisor
        int dx = i - dy * PCOLS;
        int y = h + dy - PAD;
        int x = w0 + dx - PAD;
        int v = 0;
        if ((unsigned)y < (unsigned)H_ && (unsigned)x < (unsigned)W_)
            v = (int)inb[y * W_ + x];  // trunc; vals in [0,255)
        int c = dy * PSTRIDE + dx;
        sw[c + (c >> 2)] = v;
    }

    // Group-invariant per-thread quad tables: quad q = tid + 512r covers dwords
    // 4q..4q+3 of each 4-pixel group; fe[r][u] = phi(patch offset incl. p_in).
    // phi(e + 4g) = phi(e) + 5g exactly, so group g adds a constant 5g.
    int fe[RMAX][4];
    #pragma unroll
    for (int r = 0; r < RMAX; ++r) {
        int j4 = 4 * (tid + NTHREADS * r);
        #pragma unroll
        for (int u = 0; u < 4; ++u) {
            int jj = j4 + u;
            if (jj >= 4 * d) jj = 4 * d - 1;            // clamp inactive rounds
            int p_in = (jj >= d) + (jj >= 2 * d) + (jj >= 3 * d);
            int j  = jj - p_in * d;
            int rr = j / K2;                            // const divisor 49
            int tt = j - rr * K2;
            int ry = (rr * cvmagic) >> 16;              // rr / cv (rr < 49)
            int rx = rr - ry * cv;
            int ty = tt / KT;                           // const divisor 7
            int tx = tt - ty * KT;
            int e = (offset + ry + ty) * PSTRIDE + (offset + rx + tx) + p_in;
            fe[r][u] = e + (e >> 2);                    // phi(e)
        }
    }
    __syncthreads();

    long long p0 = (long long)(b * H_ + h) * W_ + w0;
    int* op = out + p0 * (long long)d;   // 128B-aligned block base (32*d dwords)

    // Hot loop: r outer (quad id), groups inner. sw[fe + 5g] / sw[fe + 5g + 5]
    // share a base VGPR with constant dword offsets -> ds_read2_b32; two
    // independent dwordx4 stores per pair; unrolled for store-level MLP.
    #pragma unroll
    for (int r = 0; r < RMAX; ++r) {
        int q = tid + NTHREADS * r;
        if (q < d) {                     // full for r<4 at d=2401; masked r=4
            int* oq = op + 4 * q;
            #pragma unroll
            for (int g = 0; g < NG; g += 2) {
                vint4 a, c2;
                a.x  = sw[fe[r][0] + 5 * g];
                c2.x = sw[fe[r][0] + 5 * g + 5];
                a.y  = sw[fe[r][1] + 5 * g];
                c2.y = sw[fe[r][1] + 5 * g + 5];
                a.z  = sw[fe[r][2] + 5 * g];
                c2.z = sw[fe[r][2] + 5 * g + 5];
                a.w  = sw[fe[r][3] + 5 * g];
                c2.w = sw[fe[r][3] + 5 * g + 5];
                *(vint4*)(oq + g * 4 * d)       = a;
                *(vint4*)(oq + (g + 1) * 4 * d) = c2;
            }
        }
    }
}

extern "C" void kernel_launch(void* const* d_in, const int* in_sizes, int n_in,
                              void* d_out, int out_size, void* d_ws, size_t ws_size,
                              hipStream_t stream) {
    const float* in = (const float*)d_in[0];
    int* out = (int*)d_out;

    // out_size = B*H*W * cv^2 * 49
    int cv2 = out_size / (B_ * H_ * W_ * K2);
    int cv = 1;
    while (cv * cv < cv2) ++cv;
    int offset = MAX_SR - (cv - 1) / 2;
    int d = cv2 * K2;
    int cvmagic = 65536 / cv + 1;

    dim3 grid(W_ / PX, H_, B_);
    esw_kernel<<<grid, NTHREADS, 0, stream>>>(in, out, cv, offset, d, cvmagic);
}

// Round 7
// 704.970 us; speedup vs baseline: 1.0523x; 1.0275x over previous
//
#include <hip/hip_runtime.h>

// ExtractSearchWindows: out[b,h,w,rr,tt] = (uint8)Q[b, h+off+ry+ty, w+off+rx+tx],
// Q = input padded by 6; stored as INT32 (harness reads uint8 ref via int32 path).
// R3-R6 post-mortem: four different CU-side loops all ~270us (2.6 TB/s); CU-side
// issue cost is only ~5-25us -> memory-system limited. Harness fill sustains
// 6.24 TB/s with a grid-stride sweep (~9MB instantaneous window). Our private
// per-block regions put ~600MB in flight -> scattered L2 evictions. R7: swept
// window. 768 blocks; block bid does 4-pixel group g = it*768+bid, it<24; each
// iteration the chip writes one contiguous 29.5MB window (~L2 size) that sweeps.
// Per iteration: stage 13x16 neighborhood to LDS, barrier, quad loop (register
// table, 4 ds_read + 1 aligned dwordx4 store per quad).

#define KT 7
#define K2 49
#define MAX_SR 3
#define B_ 2
#define H_ 192
#define W_ 192
#define HW (H_ * W_)
#define PAD 6
#define NTHREADS 256
#define RMAX 10             // ceil(2401/256) quads per thread per group
#define PS 17               // patch row stride (13 rows x 16 cols used)
#define NBLOCKS 768         // 3 blocks/CU; 18432 groups / 768 = 24 iterations
#define NGROUPS (B_ * H_ * W_ / 4)

typedef int vint4 __attribute__((ext_vector_type(4)));

__global__ __launch_bounds__(NTHREADS) void esw_kernel(
    const float* __restrict__ in, int* __restrict__ out,
    int cv, int offset, int d /* cv*cv*49 */, int cvmagic /* 65536/cv + 1 */)
{
    __shared__ int patch[13 * PS + 4];

    const int tid = threadIdx.x;
    const int bid = blockIdx.x;

    // Group-invariant quad tables: quad q = tid + 256r covers dwords 4q..4q+3 of
    // any 4-pixel group; fe[r][u] = patch offset (incl. pixel-in-group shift).
    int fe[RMAX][4];
    #pragma unroll
    for (int r = 0; r < RMAX; ++r) {
        int j4 = 4 * (tid + NTHREADS * r);
        #pragma unroll
        for (int u = 0; u < 4; ++u) {
            int jj = j4 + u;
            if (jj >= 4 * d) jj = 4 * d - 1;            // clamp inactive rounds
            int p_in = (jj >= d) + (jj >= 2 * d) + (jj >= 3 * d);
            int j  = jj - p_in * d;
            int rr = j / K2;                            // const divisor 49
            int tt = j - rr * K2;
            int ry = (rr * cvmagic) >> 16;              // rr / cv  (rr < 49)
            int rx = rr - ry * cv;
            int ty = tt / KT;                           // const divisor 7
            int tx = tt - ty * KT;
            fe[r][u] = (offset + ry + ty) * PS + (offset + rx + tx) + p_in;
        }
    }

    for (int it = 0; it < NGROUPS / NBLOCKS; ++it) {
        const int g = it * NBLOCKS + bid;    // chip-wide contiguous window per it
        const int pix0 = 4 * g;              // W divisible by 4 -> group in one row
        const int b   = pix0 / HW;           // const divisors -> magic mul
        const int rem = pix0 - b * HW;
        const int h   = rem / W_;
        const int w   = rem - h * W_;

        __syncthreads();                     // WAR: prior iter's patch reads done
        if (tid < 13 * 16) {                 // stage 13 rows x 16 cols (w-6..w+9)
            int dy = tid >> 4;
            int dx = tid & 15;
            int y = h + dy - PAD;
            int x = w + dx - PAD;
            int v = 0;
            if ((unsigned)y < (unsigned)H_ && (unsigned)x < (unsigned)W_)
                v = (int)in[b * HW + y * W_ + x];   // uint8 trunc; vals in [0,255)
            patch[dy * PS + dx] = v;
        }
        __syncthreads();

        int* op = out + (long long)g * (long long)(4 * d);  // 16B-aligned
        #pragma unroll
        for (int r = 0; r < RMAX; ++r) {
            int q = tid + NTHREADS * r;
            if (q < d) {                     // full for r<9 at d=2401; masked r=9
                vint4 v;
                v.x = patch[fe[r][0]];
                v.y = patch[fe[r][1]];
                v.z = patch[fe[r][2]];
                v.w = patch[fe[r][3]];
                *(vint4*)(op + 4 * q) = v;
            }
        }
    }
}

extern "C" void kernel_launch(void* const* d_in, const int* in_sizes, int n_in,
                              void* d_out, int out_size, void* d_ws, size_t ws_size,
                              hipStream_t stream) {
    const float* in = (const float*)d_in[0];
    int* out = (int*)d_out;

    // out_size = B*H*W * cv^2 * 49
    int cv2 = out_size / (B_ * H_ * W_ * K2);
    int cv = 1;
    while (cv * cv < cv2) ++cv;
    int offset = MAX_SR - (cv - 1) / 2;
    int d = cv2 * K2;
    int cvmagic = 65536 / cv + 1;

    esw_kernel<<<NBLOCKS, NTHREADS, 0, stream>>>(in, out, cv, offset, d, cvmagic);
}